// Round 1
// baseline (510.033 us; speedup 1.0000x reference)
//
#include <hip/hip_runtime.h>
#include <hip/hip_bf16.h>
#include <cstdint>
#include <cstddef>

#define S_LEN   4096
#define BATCHN  4
#define DMODEL  1024
#define NHEADS  16
#define HDIM    64
#define MROWS   (S_LEN*BATCHN)   // 16384
#define NQKV    3072
#define KDIM    1024

typedef __bf16 bf16;
typedef bf16 bf16x8 __attribute__((ext_vector_type(8)));
typedef bf16 bf16x4 __attribute__((ext_vector_type(4)));
typedef float f32x4 __attribute__((ext_vector_type(4)));

__device__ __forceinline__ void gll16(const void* g, void* l) {
  __builtin_amdgcn_global_load_lds((const __attribute__((address_space(1))) unsigned*)g,
                                   (__attribute__((address_space(3))) unsigned*)l,
                                   16, 0, 0);
}

// ---------------- cast fp32 -> bf16, x4 vectorized ----------------
__global__ __launch_bounds__(256) void cast_bf16(const float* __restrict__ src,
                                                 bf16* __restrict__ dst, int n) {
  int stride = gridDim.x * blockDim.x * 4;
  for (int i = (blockIdx.x * blockDim.x + threadIdx.x) * 4; i < n; i += stride) {
    float4 f = *(const float4*)(src + i);
    bf16x4 o; o[0]=(bf16)f.x; o[1]=(bf16)f.y; o[2]=(bf16)f.z; o[3]=(bf16)f.w;
    *(bf16x4*)(dst + i) = o;
  }
}

// ---------------- GEMM C = A * B^T (+bias, +act), m97 structure ----------------
// MODE 0: QKV projection. A = (ntile<8 ? Ah : Ax), N=3072, elu+1 on cols<2048, bf16 out.
// MODE 1: output projection. A = Ah, N=1024, fp32 out.
template<int MODE>
__global__ __launch_bounds__(256) void gemm_bt(
    const bf16* __restrict__ Ah, const bf16* __restrict__ Ax,
    const bf16* __restrict__ Bw,
    const float* __restrict__ b0, const float* __restrict__ b1,
    const float* __restrict__ b2,
    void* __restrict__ Cout) {
  __shared__ __align__(16) bf16 As[128*32];
  __shared__ __align__(16) bf16 Bs[128*32];
  const int tid  = threadIdx.x;
  const int wid  = tid >> 6;
  const int lane = tid & 63;
  const int wm = wid >> 1, wn = wid & 1;
  const int mtile = blockIdx.x, ntile = blockIdx.y;
  const bf16* Ap = (MODE == 0) ? (ntile < 8 ? Ah : Ax) : Ah;
  const size_t arow0 = (size_t)mtile * 128;
  const size_t brow0 = (size_t)ntile * 128;
  f32x4 acc[4][4] = {};
  const int lr = lane >> 2;        // 0..15 row within 16-row segment
  const int lk = (lane & 3) << 3;  // 0,8,16,24 element offset in K

  for (int k0 = 0; k0 < KDIM; k0 += 32) {
    #pragma unroll
    for (int i = 0; i < 2; ++i) {
      int seg = (wid << 1) | i;    // 0..7
      gll16(Ap + (arow0 + seg*16 + lr) * KDIM + k0 + lk, As + seg*512);
      gll16(Bw + (brow0 + seg*16 + lr) * KDIM + k0 + lk, Bs + seg*512);
    }
    __syncthreads();
    bf16x8 af[4], bfv[4];
    #pragma unroll
    for (int m = 0; m < 4; ++m)
      af[m] = *(const bf16x8*)(As + (wm*64 + m*16 + (lane & 15))*32 + ((lane>>4)<<3));
    #pragma unroll
    for (int n = 0; n < 4; ++n)
      bfv[n] = *(const bf16x8*)(Bs + (wn*64 + n*16 + (lane & 15))*32 + ((lane>>4)<<3));
    #pragma unroll
    for (int m = 0; m < 4; ++m)
      #pragma unroll
      for (int n = 0; n < 4; ++n)
        acc[m][n] = __builtin_amdgcn_mfma_f32_16x16x32_bf16(af[m], bfv[n], acc[m][n], 0, 0, 0);
    __syncthreads();
  }

  #pragma unroll
  for (int m = 0; m < 4; ++m) {
    int rowb = mtile*128 + wm*64 + m*16 + ((lane >> 4) << 2);
    #pragma unroll
    for (int n = 0; n < 4; ++n) {
      int col = ntile*128 + wn*64 + n*16 + (lane & 15);
      if (MODE == 0) {
        float bias = (col < 1024) ? b0[col] : (col < 2048) ? b1[col-1024] : b2[col-2048];
        bf16* C = (bf16*)Cout;
        #pragma unroll
        for (int i = 0; i < 4; ++i) {
          float v = acc[m][n][i] + bias;
          if (col < 2048) v = (v > 0.f) ? v + 1.f : __expf(v);  // elu(x)+1
          C[(size_t)(rowb+i)*NQKV + col] = (bf16)v;
        }
      } else {
        float bias = b0[col];
        float* C = (float*)Cout;
        #pragma unroll
        for (int i = 0; i < 4; ++i)
          C[(size_t)(rowb+i)*DMODEL + col] = acc[m][n][i] + bias;
      }
    }
  }
}

// ---------------- KV = sum_s Kp^T V  and  Ksum = sum_s Kp ----------------
// grid: (64 heads, 16 s-chunks of 256). fp32 atomics into pre-zeroed buffers.
__global__ __launch_bounds__(256) void kv_reduce(const bf16* __restrict__ QKV,
                                                 float* __restrict__ KVg,
                                                 float* __restrict__ Ksumg) {
  const int head  = blockIdx.x;      // b*16+h
  const int chunk = blockIdx.y;      // 0..15
  const int b = head >> 4, hh = head & 15;
  const int tid = threadIdx.x;
  __shared__ float Kl[16*64];
  __shared__ float Vl[16*64];
  const int sr = tid >> 4;           // staging row 0..15
  const int sc = (tid & 15) << 2;    // staging col 0,4,..,60
  const int d  = tid >> 2;           // 0..63
  const int v0 = (tid & 3) << 4;     // 0,16,32,48
  float a[16] = {};
  float ks = 0.f;

  for (int it = 0; it < 16; ++it) {
    int s = chunk*256 + it*16 + sr;
    const size_t rb = ((size_t)s*BATCHN + b)*NQKV + hh*64 + sc;
    bf16x4 kv4 = *(const bf16x4*)(QKV + rb + 1024);
    bf16x4 vv4 = *(const bf16x4*)(QKV + rb + 2048);
    __syncthreads();   // previous iteration's readers done
    #pragma unroll
    for (int j = 0; j < 4; ++j) {
      Kl[sr*64 + sc + j] = (float)kv4[j];
      Vl[sr*64 + sc + j] = (float)vv4[j];
    }
    __syncthreads();
    #pragma unroll
    for (int r = 0; r < 16; ++r) {
      float kpv = Kl[r*64 + d];
      ks += kpv;
      #pragma unroll
      for (int jj = 0; jj < 4; ++jj) {
        float4 vv = *(const float4*)(Vl + r*64 + v0 + jj*4);
        a[jj*4+0] += kpv*vv.x; a[jj*4+1] += kpv*vv.y;
        a[jj*4+2] += kpv*vv.z; a[jj*4+3] += kpv*vv.w;
      }
    }
  }
  float* KVh = KVg + (size_t)head*4096;
  #pragma unroll
  for (int j = 0; j < 16; ++j) atomicAdd(&KVh[d*64 + v0 + j], a[j]);
  if ((tid & 3) == 0) atomicAdd(&Ksumg[head*64 + d], ks);
}

// ---------------- out_pre = (Qp @ KV) / Z ----------------
// grid: (64 heads, 32 s-tiles of 128). MFMA M=128 N=64 K=64.
__global__ __launch_bounds__(256) void attn_out(const bf16* __restrict__ QKV,
                                                const float* __restrict__ KVg,
                                                const float* __restrict__ Ksumg,
                                                bf16* __restrict__ OP) {
  const int head = blockIdx.x, stile = blockIdx.y;
  const int b = head >> 4, hh = head & 15;
  const int tid = threadIdx.x;
  const int wid = tid >> 6, lane = tid & 63;
  const int s0 = stile * 128;
  __shared__ __align__(16) bf16 Qs[128*64];
  __shared__ __align__(16) bf16 KVt[64*64];   // [v][d] = KV[d][v]
  __shared__ float ksum_s[64];
  __shared__ float rZ[128];

  const float* KVh = KVg + (size_t)head*4096;
  #pragma unroll
  for (int i = 0; i < 16; ++i) {
    int idx = i*256 + tid;
    int dd = idx >> 6, vv = idx & 63;
    KVt[vv*64 + dd] = (bf16)KVh[idx];
  }
  if (tid < 64) ksum_s[tid] = Ksumg[head*64 + tid];
  #pragma unroll
  for (int p = 0; p < 4; ++p) {
    int row = p*32 + wid*8 + (lane >> 3);
    gll16(QKV + ((size_t)(s0+row)*BATCHN + b)*NQKV + hh*64 + ((lane&7)<<3),
          Qs + (p*32 + wid*8)*64);
  }
  __syncthreads();

  if (tid < 128) {
    float z = 0.f;
    #pragma unroll
    for (int dd = 0; dd < 64; ++dd) z += (float)Qs[tid*64 + dd] * ksum_s[dd];
    rZ[tid] = 1.f / (z + 1e-6f);
  }
  __syncthreads();

  f32x4 acc[2][4] = {};
  #pragma unroll
  for (int ksb = 0; ksb < 2; ++ksb) {
    bf16x8 af[2], bv[4];
    #pragma unroll
    for (int m = 0; m < 2; ++m)
      af[m] = *(const bf16x8*)(Qs + (wid*32 + m*16 + (lane & 15))*64 + ksb*32 + ((lane>>4)<<3));
    #pragma unroll
    for (int n = 0; n < 4; ++n)
      bv[n] = *(const bf16x8*)(KVt + (n*16 + (lane & 15))*64 + ksb*32 + ((lane>>4)<<3));
    #pragma unroll
    for (int m = 0; m < 2; ++m)
      #pragma unroll
      for (int n = 0; n < 4; ++n)
        acc[m][n] = __builtin_amdgcn_mfma_f32_16x16x32_bf16(af[m], bv[n], acc[m][n], 0, 0, 0);
  }

  #pragma unroll
  for (int m = 0; m < 2; ++m)
    #pragma unroll
    for (int n = 0; n < 4; ++n)
      #pragma unroll
      for (int i = 0; i < 4; ++i) {
        int row = wid*32 + m*16 + ((lane >> 4) << 2) + i;
        int vv  = n*16 + (lane & 15);
        float val = acc[m][n][i] * rZ[row];
        OP[((size_t)(s0+row)*BATCHN + b)*DMODEL + hh*64 + vv] = (bf16)val;
      }
}

// ---------------- launch ----------------
extern "C" void kernel_launch(void* const* d_in, const int* in_sizes, int n_in,
                              void* d_out, int out_size, void* d_ws, size_t ws_size,
                              hipStream_t stream) {
  const float* h  = (const float*)d_in[0];
  const float* x  = (const float*)d_in[1];
  const float* Wq = (const float*)d_in[2];
  const float* bq = (const float*)d_in[3];
  const float* Wk = (const float*)d_in[4];
  const float* bk = (const float*)d_in[5];
  const float* Wv = (const float*)d_in[6];
  const float* bv = (const float*)d_in[7];
  const float* Wo = (const float*)d_in[8];
  const float* bo = (const float*)d_in[9];

  char* ws = (char*)d_ws;
  bf16*  hbf  = (bf16*)(ws);                    // 33,554,432 B
  bf16*  xbf  = (bf16*)(ws + 33554432);         // 33,554,432 B
  bf16*  wcat = (bf16*)(ws + 67108864);         //  6,291,456 B  [3072][1024]
  bf16*  wob  = (bf16*)(ws + 73400320);         //  2,097,152 B  [1024][1024]
  bf16*  qkv  = (bf16*)(ws + 75497472);         // 100,663,296 B [16384][3072]
  float* kvb  = (float*)(ws + 176160768);       //  1,048,576 B  [64][64][64]
  float* ksb  = (float*)(ws + 177209344);       //     16,384 B  [64][64]
  bf16*  op   = (bf16*)(ws + 177225728);        // 33,554,432 B  [16384][1024]
  // total: 210,780,160 B

  cast_bf16<<<dim3(2048), 256, 0, stream>>>(h, hbf, MROWS*KDIM);
  cast_bf16<<<dim3(2048), 256, 0, stream>>>(x, xbf, MROWS*KDIM);
  cast_bf16<<<dim3(512),  256, 0, stream>>>(Wq, wcat,           1048576);
  cast_bf16<<<dim3(512),  256, 0, stream>>>(Wk, wcat + 1048576, 1048576);
  cast_bf16<<<dim3(512),  256, 0, stream>>>(Wv, wcat + 2097152, 1048576);
  cast_bf16<<<dim3(512),  256, 0, stream>>>(Wo, wob,            1048576);

  hipMemsetAsync(kvb, 0, 1048576 + 16384, stream);

  gemm_bt<0><<<dim3(128, 24), 256, 0, stream>>>(hbf, xbf, wcat, bq, bk, bv, qkv);
  kv_reduce<<<dim3(64, 16), 256, 0, stream>>>(qkv, kvb, ksb);
  attn_out<<<dim3(64, 32), 256, 0, stream>>>(qkv, kvb, ksb, op);
  gemm_bt<1><<<dim3(128, 8), 256, 0, stream>>>(op, nullptr, wob, bo, nullptr, nullptr, d_out);
}

// Round 2
// 335.293 us; speedup vs baseline: 1.5212x; 1.5212x over previous
//
#include <hip/hip_runtime.h>
#include <hip/hip_bf16.h>
#include <cstdint>
#include <cstddef>

#define S_LEN   4096
#define BATCHN  4
#define DMODEL  1024
#define NHEADS  16
#define HDIM    64
#define MROWS   (S_LEN*BATCHN)   // 16384
#define NQKV    3072
#define KDIM    1024
#define KSPLIT  8
#define TP_PAD  66

typedef __bf16 bf16;
typedef bf16 bf16x8 __attribute__((ext_vector_type(8)));
typedef bf16 bf16x4 __attribute__((ext_vector_type(4)));
typedef float f32x4 __attribute__((ext_vector_type(4)));

__device__ __forceinline__ void gll16(const void* g, void* l) {
  __builtin_amdgcn_global_load_lds((const __attribute__((address_space(1))) unsigned*)g,
                                   (__attribute__((address_space(3))) unsigned*)l,
                                   16, 0, 0);
}

// ---------------- cast fp32 -> bf16, x4 vectorized ----------------
__global__ __launch_bounds__(256) void cast_bf16(const float* __restrict__ src,
                                                 bf16* __restrict__ dst, int n) {
  int stride = gridDim.x * blockDim.x * 4;
  for (int i = (blockIdx.x * blockDim.x + threadIdx.x) * 4; i < n; i += stride) {
    float4 f = *(const float4*)(src + i);
    bf16x4 o; o[0]=(bf16)f.x; o[1]=(bf16)f.y; o[2]=(bf16)f.z; o[3]=(bf16)f.w;
    *(bf16x4*)(dst + i) = o;
  }
}

// ---------------- GEMM C = A * B^T (+bias, +act), m97 structure ----------------
template<int MODE>
__global__ __launch_bounds__(256) void gemm_bt(
    const bf16* __restrict__ Ah, const bf16* __restrict__ Ax,
    const bf16* __restrict__ Bw,
    const float* __restrict__ b0, const float* __restrict__ b1,
    const float* __restrict__ b2,
    void* __restrict__ Cout) {
  __shared__ __align__(16) bf16 As[128*32];
  __shared__ __align__(16) bf16 Bs[128*32];
  const int tid  = threadIdx.x;
  const int wid  = tid >> 6;
  const int lane = tid & 63;
  const int wm = wid >> 1, wn = wid & 1;
  const int mtile = blockIdx.x, ntile = blockIdx.y;
  const bf16* Ap = (MODE == 0) ? (ntile < 8 ? Ah : Ax) : Ah;
  const size_t arow0 = (size_t)mtile * 128;
  const size_t brow0 = (size_t)ntile * 128;
  f32x4 acc[4][4] = {};
  const int lr = lane >> 2;        // 0..15 row within 16-row segment
  const int lk = (lane & 3) << 3;  // 0,8,16,24 element offset in K

  for (int k0 = 0; k0 < KDIM; k0 += 32) {
    #pragma unroll
    for (int i = 0; i < 2; ++i) {
      int seg = (wid << 1) | i;    // 0..7
      gll16(Ap + (arow0 + seg*16 + lr) * KDIM + k0 + lk, As + seg*512);
      gll16(Bw + (brow0 + seg*16 + lr) * KDIM + k0 + lk, Bs + seg*512);
    }
    __syncthreads();
    bf16x8 af[4], bfv[4];
    #pragma unroll
    for (int m = 0; m < 4; ++m)
      af[m] = *(const bf16x8*)(As + (wm*64 + m*16 + (lane & 15))*32 + ((lane>>4)<<3));
    #pragma unroll
    for (int n = 0; n < 4; ++n)
      bfv[n] = *(const bf16x8*)(Bs + (wn*64 + n*16 + (lane & 15))*32 + ((lane>>4)<<3));
    #pragma unroll
    for (int m = 0; m < 4; ++m)
      #pragma unroll
      for (int n = 0; n < 4; ++n)
        acc[m][n] = __builtin_amdgcn_mfma_f32_16x16x32_bf16(af[m], bfv[n], acc[m][n], 0, 0, 0);
    __syncthreads();
  }

  #pragma unroll
  for (int m = 0; m < 4; ++m) {
    int rowb = mtile*128 + wm*64 + m*16 + ((lane >> 4) << 2);
    #pragma unroll
    for (int n = 0; n < 4; ++n) {
      int col = ntile*128 + wn*64 + n*16 + (lane & 15);
      if (MODE == 0) {
        float bias = (col < 1024) ? b0[col] : (col < 2048) ? b1[col-1024] : b2[col-2048];
        bf16* C = (bf16*)Cout;
        #pragma unroll
        for (int i = 0; i < 4; ++i) {
          float v = acc[m][n][i] + bias;
          if (col < 2048) v = (v > 0.f) ? v + 1.f : __expf(v);  // elu(x)+1
          C[(size_t)(rowb+i)*NQKV + col] = (bf16)v;
        }
      } else {
        float bias = b0[col];
        float* C = (float*)Cout;
        #pragma unroll
        for (int i = 0; i < 4; ++i)
          C[(size_t)(rowb+i)*DMODEL + col] = acc[m][n][i] + bias;
      }
    }
  }
}

// ---------------- transpose K,V halves of qkv into [bh][d][s]; Ksum partials ----------------
// grid: (64 bh, 32 s-chunks of 128), block 256
__global__ __launch_bounds__(256) void transpose_kv(const bf16* __restrict__ QKV,
                                                    bf16* __restrict__ Kt,
                                                    bf16* __restrict__ Vt,
                                                    float* __restrict__ Ksumg) {
  const int bh = blockIdx.x;
  const int sc0 = blockIdx.y * 128;
  const int b = bh >> 4, hh = bh & 15;
  const int tid = threadIdx.x;
  __shared__ bf16 Kl[128*TP_PAD];
  __shared__ bf16 Vl[128*TP_PAD];
  __shared__ float red[256];

  // load phase: rows (s) x 64 cols (d); thread t: sr=(t>>3)+32i, chunk c=t&7 (8 bf16 each)
  const int c = tid & 7;
  #pragma unroll
  for (int i = 0; i < 4; ++i) {
    int sr = (tid >> 3) + i * 32;
    size_t gaddr = ((size_t)(sc0 + sr) * BATCHN + b) * NQKV + 1024 + hh*64 + c*8;
    bf16x8 kv = *(const bf16x8*)(QKV + gaddr);          // K part
    bf16x8 vv = *(const bf16x8*)(QKV + gaddr + 1024);   // V part
    *(bf16x8*)(Kl + sr*TP_PAD + c*8) = kv;
    *(bf16x8*)(Vl + sr*TP_PAD + c*8) = vv;
  }
  __syncthreads();

  // store phase: thread t: d=t&63, s-chunk sc=(t>>6)+4i; gather 8 s-values per chunk
  const int d = tid & 63;
  float ks = 0.f;
  #pragma unroll
  for (int i = 0; i < 4; ++i) {
    int sc = (tid >> 6) + i * 4;
    bf16x8 ko, vo;
    #pragma unroll
    for (int j = 0; j < 8; ++j) {
      bf16 kvv = Kl[(sc*8 + j)*TP_PAD + d];
      ko[j] = kvv;
      ks += (float)kvv;
      vo[j] = Vl[(sc*8 + j)*TP_PAD + d];
    }
    size_t obase = (size_t)bh * 64 * S_LEN + (size_t)d * S_LEN + sc0 + sc*8;
    *(bf16x8*)(Kt + obase) = ko;
    *(bf16x8*)(Vt + obase) = vo;
  }
  red[tid] = ks;
  __syncthreads();
  if (tid < 64) {
    float s = red[tid] + red[tid+64] + red[tid+128] + red[tid+192];
    atomicAdd(&Ksumg[bh*64 + tid], s);
  }
}

// ---------------- KV[bh][d][v] = sum_s Kt[bh][d][s] * Vt[bh][v][s], split-K ----------------
// grid: (64 bh, KSPLIT), block 256 (4 waves: wm=wid>>1, wn=wid&1)
__global__ __launch_bounds__(256) void kv_gemm(const bf16* __restrict__ Kt,
                                               const bf16* __restrict__ Vt,
                                               float* __restrict__ KVg) {
  const int bh = blockIdx.x;
  const int k0base = blockIdx.y * (S_LEN / KSPLIT);
  const int tid = threadIdx.x, wid = tid >> 6, lane = tid & 63;
  const int wm = wid >> 1, wn = wid & 1;
  __shared__ __align__(16) bf16 Ks[64*64];
  __shared__ __align__(16) bf16 Vs[64*64];
  const bf16* Kh = Kt + (size_t)bh * 64 * S_LEN;
  const bf16* Vh = Vt + (size_t)bh * 64 * S_LEN;
  f32x4 acc[2][2] = {};

  for (int k0 = k0base; k0 < k0base + S_LEN/KSPLIT; k0 += 64) {
    #pragma unroll
    for (int j = 0; j < 4; ++j) {
      int cchunk = wid*4 + j;                 // 0..15; <8 -> K rows, >=8 -> V rows
      int r = (cchunk & 7) * 8 + (lane >> 3); // row 0..63
      int colb = (lane & 7) * 16;             // byte col within 128B row
      int scol = colb ^ ((r & 7) << 4);       // pre-swizzled source col (involution)
      const bf16* src = (cchunk < 8) ? Kh : Vh;
      bf16* dst = ((cchunk < 8) ? Ks : Vs) + (size_t)(cchunk & 7) * 8 * 64;
      gll16(src + (size_t)r * S_LEN + k0 + (scol >> 1), dst);
    }
    __syncthreads();
    #pragma unroll
    for (int ksb = 0; ksb < 2; ++ksb) {
      bf16x8 af[2], bv[2];
      #pragma unroll
      for (int m = 0; m < 2; ++m) {
        int R = wm*32 + m*16 + (lane & 15);
        int cb = (ksb*64 + ((lane >> 4) << 4)) ^ ((R & 7) << 4);
        af[m] = *(const bf16x8*)((const char*)Ks + R*128 + cb);
      }
      #pragma unroll
      for (int n = 0; n < 2; ++n) {
        int R = wn*32 + n*16 + (lane & 15);
        int cb = (ksb*64 + ((lane >> 4) << 4)) ^ ((R & 7) << 4);
        bv[n] = *(const bf16x8*)((const char*)Vs + R*128 + cb);
      }
      #pragma unroll
      for (int m = 0; m < 2; ++m)
        #pragma unroll
        for (int n = 0; n < 2; ++n)
          acc[m][n] = __builtin_amdgcn_mfma_f32_16x16x32_bf16(af[m], bv[n], acc[m][n], 0, 0, 0);
    }
    __syncthreads();
  }

  #pragma unroll
  for (int m = 0; m < 2; ++m)
    #pragma unroll
    for (int n = 0; n < 2; ++n)
      #pragma unroll
      for (int i = 0; i < 4; ++i) {
        int dd = wm*32 + m*16 + ((lane >> 4) << 2) + i;
        int vv = wn*32 + n*16 + (lane & 15);
        atomicAdd(&KVg[(size_t)bh*4096 + dd*64 + vv], acc[m][n][i]);
      }
}

// ---------------- out_pre = (Qp @ KV) / Z ----------------
// grid: (64 heads, 32 s-tiles of 128). MFMA M=128 N=64 K=64.
__global__ __launch_bounds__(256) void attn_out(const bf16* __restrict__ QKV,
                                                const float* __restrict__ KVg,
                                                const float* __restrict__ Ksumg,
                                                bf16* __restrict__ OP) {
  const int head = blockIdx.x, stile = blockIdx.y;
  const int b = head >> 4, hh = head & 15;
  const int tid = threadIdx.x;
  const int wid = tid >> 6, lane = tid & 63;
  const int s0 = stile * 128;
  __shared__ __align__(16) bf16 Qs[128*64];
  __shared__ __align__(16) bf16 KVt[64*64];   // [v][d] = KV[d][v]
  __shared__ float ksum_s[64];
  __shared__ float rZ[128];

  const float* KVh = KVg + (size_t)head*4096;
  #pragma unroll
  for (int i = 0; i < 16; ++i) {
    int idx = i*256 + tid;
    int dd = idx >> 6, vv = idx & 63;
    KVt[vv*64 + dd] = (bf16)KVh[idx];
  }
  if (tid < 64) ksum_s[tid] = Ksumg[head*64 + tid];
  #pragma unroll
  for (int p = 0; p < 4; ++p) {
    int row = p*32 + wid*8 + (lane >> 3);
    gll16(QKV + ((size_t)(s0+row)*BATCHN + b)*NQKV + hh*64 + ((lane&7)<<3),
          Qs + (p*32 + wid*8)*64);
  }
  __syncthreads();

  if (tid < 128) {
    float z = 0.f;
    #pragma unroll
    for (int dd = 0; dd < 64; ++dd) z += (float)Qs[tid*64 + dd] * ksum_s[dd];
    rZ[tid] = 1.f / (z + 1e-6f);
  }
  __syncthreads();

  f32x4 acc[2][4] = {};
  #pragma unroll
  for (int ksb = 0; ksb < 2; ++ksb) {
    bf16x8 af[2], bv[4];
    #pragma unroll
    for (int m = 0; m < 2; ++m)
      af[m] = *(const bf16x8*)(Qs + (wid*32 + m*16 + (lane & 15))*64 + ksb*32 + ((lane>>4)<<3));
    #pragma unroll
    for (int n = 0; n < 4; ++n)
      bv[n] = *(const bf16x8*)(KVt + (n*16 + (lane & 15))*64 + ksb*32 + ((lane>>4)<<3));
    #pragma unroll
    for (int m = 0; m < 2; ++m)
      #pragma unroll
      for (int n = 0; n < 4; ++n)
        acc[m][n] = __builtin_amdgcn_mfma_f32_16x16x32_bf16(af[m], bv[n], acc[m][n], 0, 0, 0);
  }

  #pragma unroll
  for (int m = 0; m < 2; ++m)
    #pragma unroll
    for (int n = 0; n < 4; ++n)
      #pragma unroll
      for (int i = 0; i < 4; ++i) {
        int row = wid*32 + m*16 + ((lane >> 4) << 2) + i;
        int vv  = n*16 + (lane & 15);
        float val = acc[m][n][i] * rZ[row];
        OP[((size_t)(s0+row)*BATCHN + b)*DMODEL + hh*64 + vv] = (bf16)val;
      }
}

// ---------------- launch ----------------
extern "C" void kernel_launch(void* const* d_in, const int* in_sizes, int n_in,
                              void* d_out, int out_size, void* d_ws, size_t ws_size,
                              hipStream_t stream) {
  const float* h  = (const float*)d_in[0];
  const float* x  = (const float*)d_in[1];
  const float* Wq = (const float*)d_in[2];
  const float* bq = (const float*)d_in[3];
  const float* Wk = (const float*)d_in[4];
  const float* bk = (const float*)d_in[5];
  const float* Wv = (const float*)d_in[6];
  const float* bv = (const float*)d_in[7];
  const float* Wo = (const float*)d_in[8];
  const float* bo = (const float*)d_in[9];

  char* ws = (char*)d_ws;
  bf16*  hbf  = (bf16*)(ws);                    // 33,554,432 B  (reused as Kt)
  bf16*  xbf  = (bf16*)(ws + 33554432);         // 33,554,432 B  (reused as Vt)
  bf16*  wcat = (bf16*)(ws + 67108864);         //  6,291,456 B  [3072][1024]
  bf16*  wob  = (bf16*)(ws + 73400320);         //  2,097,152 B  [1024][1024]
  bf16*  qkv  = (bf16*)(ws + 75497472);         // 100,663,296 B [16384][3072]
  float* kvb  = (float*)(ws + 176160768);       //  1,048,576 B  [64][64][64]
  float* ksb  = (float*)(ws + 177209344);       //     16,384 B  [64][64]
  bf16*  op   = (bf16*)(ws + 177225728);        // 33,554,432 B  [16384][1024]
  // total: 210,780,160 B

  bf16* Kt = hbf;   // [64 bh][64 d][4096 s] — hbf dead after QKV GEMM
  bf16* Vt = xbf;   // [64 bh][64 v][4096 s] — xbf dead after QKV GEMM

  cast_bf16<<<dim3(2048), 256, 0, stream>>>(h, hbf, MROWS*KDIM);
  cast_bf16<<<dim3(2048), 256, 0, stream>>>(x, xbf, MROWS*KDIM);
  cast_bf16<<<dim3(512),  256, 0, stream>>>(Wq, wcat,           1048576);
  cast_bf16<<<dim3(512),  256, 0, stream>>>(Wk, wcat + 1048576, 1048576);
  cast_bf16<<<dim3(512),  256, 0, stream>>>(Wv, wcat + 2097152, 1048576);
  cast_bf16<<<dim3(512),  256, 0, stream>>>(Wo, wob,            1048576);

  hipMemsetAsync(kvb, 0, 1048576 + 16384, stream);

  gemm_bt<0><<<dim3(128, 24), 256, 0, stream>>>(hbf, xbf, wcat, bq, bk, bv, qkv);
  transpose_kv<<<dim3(64, 32), 256, 0, stream>>>(qkv, Kt, Vt, ksb);
  kv_gemm<<<dim3(64, KSPLIT), 256, 0, stream>>>(Kt, Vt, kvb);
  attn_out<<<dim3(64, 32), 256, 0, stream>>>(qkv, kvb, ksb, op);
  gemm_bt<1><<<dim3(128, 8), 256, 0, stream>>>(op, nullptr, wob, bo, nullptr, nullptr, d_out);
}

// Round 3
// 304.892 us; speedup vs baseline: 1.6728x; 1.0997x over previous
//
#include <hip/hip_runtime.h>
#include <hip/hip_bf16.h>
#include <cstdint>
#include <cstddef>

#define S_LEN   4096
#define BATCHN  4
#define DMODEL  1024
#define NHEADS  16
#define HDIM    64
#define MROWS   (S_LEN*BATCHN)   // 16384
#define NQKV    3072
#define KDIM    1024
#define KSPLIT  8
#define TP_PAD  66
#define NT      (KDIM/64)        // 16 K-tiles of 64

typedef __bf16 bf16;
typedef bf16 bf16x8 __attribute__((ext_vector_type(8)));
typedef bf16 bf16x4 __attribute__((ext_vector_type(4)));
typedef float f32x4 __attribute__((ext_vector_type(4)));

#define MFMA_BF16(a,b,c) __builtin_amdgcn_mfma_f32_16x16x32_bf16(a,b,c,0,0,0)

__device__ __forceinline__ void gll16(const void* g, void* l) {
  __builtin_amdgcn_global_load_lds((const __attribute__((address_space(1))) unsigned*)g,
                                   (__attribute__((address_space(3))) unsigned*)l,
                                   16, 0, 0);
}

// ---------------- cast fp32 -> bf16, x4 vectorized ----------------
__global__ __launch_bounds__(256) void cast_bf16(const float* __restrict__ src,
                                                 bf16* __restrict__ dst, int n) {
  int stride = gridDim.x * blockDim.x * 4;
  for (int i = (blockIdx.x * blockDim.x + threadIdx.x) * 4; i < n; i += stride) {
    float4 f = *(const float4*)(src + i);
    bf16x4 o; o[0]=(bf16)f.x; o[1]=(bf16)f.y; o[2]=(bf16)f.z; o[3]=(bf16)f.w;
    *(bf16x4*)(dst + i) = o;
  }
}

// ---------------- 256x256 8-wave GEMM, BK=64, T2 swizzle + counted vmcnt ----------------
// LDS tile layout (per 32KB A or B buffer): subtile st = (row>>4)*2 + (col>>5),
// local lp_pre = (row&15)*64 + (col&31)*2, phys lp = lp_pre ^ (((lp_pre>>9)&1)<<5).
// Stage order (16B chunks, o in [0,4096)): [A ks0 | B ks0 qn0 | B ks0 qn1 | A ks1 | B ks1 qn0 | B ks1 qn1]
// Phase q of tile t stages chunks o in [1024q, 1024q+1024) for tile t+1.
// Drains: vmcnt(4) at phase 0 and phase 2 (covers stages issued 2 phases earlier).
__device__ __forceinline__ void decodeStage(int o, int& dstOff, int& gElem, int& isB) {
  int ch = o & 63;
  int st;
  if (o < 1024)      { isB = 0; st = (o >> 6) << 1; }
  else if (o < 1536) { isB = 1; int r8 = (o - 1024) >> 6; int rg = ((r8 >> 1) << 2) | (r8 & 1); st = rg << 1; }
  else if (o < 2048) { isB = 1; int r8 = (o - 1536) >> 6; int rg = (((r8 >> 1) << 2) | (r8 & 1)) + 2; st = rg << 1; }
  else if (o < 3072) { isB = 0; st = (((o - 2048) >> 6) << 1) | 1; }
  else if (o < 3584) { isB = 1; int r8 = (o - 3072) >> 6; int rg = ((r8 >> 1) << 2) | (r8 & 1); st = (rg << 1) | 1; }
  else               { isB = 1; int r8 = (o - 3584) >> 6; int rg = (((r8 >> 1) << 2) | (r8 & 1)) + 2; st = (rg << 1) | 1; }
  int lp   = ch << 4;                          // physical byte within subtile
  int lpre = lp ^ (((lp >> 9) & 1) << 5);      // logical byte (involution)
  int row  = ((st >> 1) << 4) | (lpre >> 6);
  int col  = ((st & 1) << 5) | ((lpre & 63) >> 1);
  dstOff = (st << 10) | lp;
  gElem  = row * KDIM + col;
}

template<int MODE>
__global__ __launch_bounds__(512, 2) void gemm256(
    const bf16* __restrict__ Ah, const bf16* __restrict__ Ax,
    const bf16* __restrict__ Bw,
    const float* __restrict__ b0, const float* __restrict__ b1,
    const float* __restrict__ b2,
    void* __restrict__ Cout) {
  __shared__ __align__(16) char smem[2][65536];   // [dbuf][A 32KB | B 32KB]
  const int tid  = threadIdx.x;
  const int wid  = tid >> 6, lane = tid & 63;
  const int wm   = wid >> 2, wn = wid & 3;        // 2M x 4N waves, each owns 128x64
  const int NTL  = (MODE == 0) ? 12 : 4;
  const int nwg  = gridDim.x;
  const int bid  = blockIdx.x;
  const int wg   = (bid & 7) * (nwg >> 3) + (bid >> 3);   // bijective XCD swizzle (nwg%8==0)
  const int ntile = wg % NTL, mtile = wg / NTL;

  const bf16* Ap = (MODE == 0) ? ((ntile < 4) ? Ah : Ax) : Ah;
  const bf16* Abase = Ap + (size_t)mtile * 256 * KDIM;
  const bf16* Bbase = Bw + (size_t)ntile * 256 * KDIM;

  // per-thread stage slots: 4 phases x 2 chunks
  const bf16* sPtr[4][2];
  int sDst[4][2];
  #pragma unroll
  for (int q = 0; q < 4; ++q)
    #pragma unroll
    for (int j = 0; j < 2; ++j) {
      int o = q * 1024 + j * 512 + tid;
      int dof, ge, isB;
      decodeStage(o, dof, ge, isB);
      sPtr[q][j] = (isB ? Bbase : Abase) + ge;
      sDst[q][j] = (isB << 15) | dof;
    }

  // per-lane fragment byte offset within a subtile (swizzled)
  const int lpre = ((lane & 15) << 6) | ((lane >> 4) << 4);
  const int lpA  = lpre ^ (((lane >> 3) & 1) << 5);

  f32x4 acc[8][4] = {};
  bf16x8 aF[8], bF[2];

  // prologue: stage tile 0 into smem[0] (issue order q-major = drain order)
  #pragma unroll
  for (int q = 0; q < 4; ++q)
    #pragma unroll
    for (int j = 0; j < 2; ++j)
      gll16(sPtr[q][j], smem[0] + sDst[q][j]);

  for (int t = 0; t < NT; ++t) {
    char* rbuf = smem[t & 1];
    char* wbuf = smem[(t & 1) ^ 1];
    const int knext = (t + 1) * 64;
    const bool more = (t + 1 < NT);

    // ---- phase 0: ks=0, qn=0 ----
    asm volatile("s_waitcnt vmcnt(4)" ::: "memory");
    __builtin_amdgcn_s_barrier();
    __builtin_amdgcn_sched_barrier(0);
    #pragma unroll
    for (int m = 0; m < 8; ++m)
      aF[m] = *(const bf16x8*)(rbuf + (((wm * 8 + m) << 1) << 10) + lpA);
    #pragma unroll
    for (int n = 0; n < 2; ++n)
      bF[n] = *(const bf16x8*)(rbuf + 32768 + (((wn * 4 + n) << 1) << 10) + lpA);
    if (more) { gll16(sPtr[0][0] + knext, wbuf + sDst[0][0]);
                gll16(sPtr[0][1] + knext, wbuf + sDst[0][1]); }
    __builtin_amdgcn_s_setprio(1);
    #pragma unroll
    for (int m = 0; m < 8; ++m) {
      acc[m][0] = MFMA_BF16(aF[m], bF[0], acc[m][0]);
      acc[m][1] = MFMA_BF16(aF[m], bF[1], acc[m][1]);
    }
    __builtin_amdgcn_s_setprio(0);

    // ---- phase 1: ks=0, qn=1 ----
    __builtin_amdgcn_s_barrier();
    __builtin_amdgcn_sched_barrier(0);
    #pragma unroll
    for (int n = 0; n < 2; ++n)
      bF[n] = *(const bf16x8*)(rbuf + 32768 + (((wn * 4 + 2 + n) << 1) << 10) + lpA);
    if (more) { gll16(sPtr[1][0] + knext, wbuf + sDst[1][0]);
                gll16(sPtr[1][1] + knext, wbuf + sDst[1][1]); }
    __builtin_amdgcn_s_setprio(1);
    #pragma unroll
    for (int m = 0; m < 8; ++m) {
      acc[m][2] = MFMA_BF16(aF[m], bF[0], acc[m][2]);
      acc[m][3] = MFMA_BF16(aF[m], bF[1], acc[m][3]);
    }
    __builtin_amdgcn_s_setprio(0);

    // ---- phase 2: ks=1, qn=0 ----
    if (t == NT - 1) asm volatile("s_waitcnt vmcnt(0)" ::: "memory");
    else             asm volatile("s_waitcnt vmcnt(4)" ::: "memory");
    __builtin_amdgcn_s_barrier();
    __builtin_amdgcn_sched_barrier(0);
    #pragma unroll
    for (int m = 0; m < 8; ++m)
      aF[m] = *(const bf16x8*)(rbuf + ((((wm * 8 + m) << 1) | 1) << 10) + lpA);
    #pragma unroll
    for (int n = 0; n < 2; ++n)
      bF[n] = *(const bf16x8*)(rbuf + 32768 + ((((wn * 4 + n) << 1) | 1) << 10) + lpA);
    if (more) { gll16(sPtr[2][0] + knext, wbuf + sDst[2][0]);
                gll16(sPtr[2][1] + knext, wbuf + sDst[2][1]); }
    __builtin_amdgcn_s_setprio(1);
    #pragma unroll
    for (int m = 0; m < 8; ++m) {
      acc[m][0] = MFMA_BF16(aF[m], bF[0], acc[m][0]);
      acc[m][1] = MFMA_BF16(aF[m], bF[1], acc[m][1]);
    }
    __builtin_amdgcn_s_setprio(0);

    // ---- phase 3: ks=1, qn=1 ----
    __builtin_amdgcn_s_barrier();
    __builtin_amdgcn_sched_barrier(0);
    #pragma unroll
    for (int n = 0; n < 2; ++n)
      bF[n] = *(const bf16x8*)(rbuf + 32768 + ((((wn * 4 + 2 + n) << 1) | 1) << 10) + lpA);
    if (more) { gll16(sPtr[3][0] + knext, wbuf + sDst[3][0]);
                gll16(sPtr[3][1] + knext, wbuf + sDst[3][1]); }
    __builtin_amdgcn_s_setprio(1);
    #pragma unroll
    for (int m = 0; m < 8; ++m) {
      acc[m][2] = MFMA_BF16(aF[m], bF[0], acc[m][2]);
      acc[m][3] = MFMA_BF16(aF[m], bF[1], acc[m][3]);
    }
    __builtin_amdgcn_s_setprio(0);
  }

  // epilogue
  #pragma unroll
  for (int m = 0; m < 8; ++m) {
    const int rowb = mtile * 256 + wm * 128 + m * 16 + ((lane >> 4) << 2);
    #pragma unroll
    for (int nl = 0; nl < 4; ++nl) {
      const int col = ntile * 256 + wn * 64 + nl * 16 + (lane & 15);
      if (MODE == 0) {
        const float bias = (col < 1024) ? b0[col] : (col < 2048) ? b1[col - 1024] : b2[col - 2048];
        bf16* C = (bf16*)Cout;
        #pragma unroll
        for (int i = 0; i < 4; ++i) {
          float v = acc[m][nl][i] + bias;
          if (col < 2048) v = (v > 0.f) ? v + 1.f : __expf(v);   // elu(x)+1
          C[(size_t)(rowb + i) * NQKV + col] = (bf16)v;
        }
      } else {
        const float bias = b0[col];
        float* C = (float*)Cout;
        #pragma unroll
        for (int i = 0; i < 4; ++i)
          C[(size_t)(rowb + i) * DMODEL + col] = acc[m][nl][i] + bias;
      }
    }
  }
}

// ---------------- transpose K,V halves of qkv into [bh][d][s]; Ksum partials ----------------
__global__ __launch_bounds__(256) void transpose_kv(const bf16* __restrict__ QKV,
                                                    bf16* __restrict__ Kt,
                                                    bf16* __restrict__ Vt,
                                                    float* __restrict__ Ksumg) {
  const int bh = blockIdx.x;
  const int sc0 = blockIdx.y * 128;
  const int b = bh >> 4, hh = bh & 15;
  const int tid = threadIdx.x;
  __shared__ bf16 Kl[128*TP_PAD];
  __shared__ bf16 Vl[128*TP_PAD];
  __shared__ float red[256];

  const int c = tid & 7;
  #pragma unroll
  for (int i = 0; i < 4; ++i) {
    int sr = (tid >> 3) + i * 32;
    size_t gaddr = ((size_t)(sc0 + sr) * BATCHN + b) * NQKV + 1024 + hh*64 + c*8;
    bf16x8 kv = *(const bf16x8*)(QKV + gaddr);
    bf16x8 vv = *(const bf16x8*)(QKV + gaddr + 1024);
    *(bf16x8*)(Kl + sr*TP_PAD + c*8) = kv;
    *(bf16x8*)(Vl + sr*TP_PAD + c*8) = vv;
  }
  __syncthreads();

  const int d = tid & 63;
  float ks = 0.f;
  #pragma unroll
  for (int i = 0; i < 4; ++i) {
    int sc = (tid >> 6) + i * 4;
    bf16x8 ko, vo;
    #pragma unroll
    for (int j = 0; j < 8; ++j) {
      bf16 kvv = Kl[(sc*8 + j)*TP_PAD + d];
      ko[j] = kvv;
      ks += (float)kvv;
      vo[j] = Vl[(sc*8 + j)*TP_PAD + d];
    }
    size_t obase = (size_t)bh * 64 * S_LEN + (size_t)d * S_LEN + sc0 + sc*8;
    *(bf16x8*)(Kt + obase) = ko;
    *(bf16x8*)(Vt + obase) = vo;
  }
  red[tid] = ks;
  __syncthreads();
  if (tid < 64) {
    float s = red[tid] + red[tid+64] + red[tid+128] + red[tid+192];
    atomicAdd(&Ksumg[bh*64 + tid], s);
  }
}

// ---------------- KV[bh][d][v] = sum_s Kt[bh][d][s] * Vt[bh][v][s], split-K ----------------
__global__ __launch_bounds__(256) void kv_gemm(const bf16* __restrict__ Kt,
                                               const bf16* __restrict__ Vt,
                                               float* __restrict__ KVg) {
  const int bh = blockIdx.x;
  const int k0base = blockIdx.y * (S_LEN / KSPLIT);
  const int tid = threadIdx.x, wid = tid >> 6, lane = tid & 63;
  const int wm = wid >> 1, wn = wid & 1;
  __shared__ __align__(16) bf16 Ks[64*64];
  __shared__ __align__(16) bf16 Vs[64*64];
  const bf16* Kh = Kt + (size_t)bh * 64 * S_LEN;
  const bf16* Vh = Vt + (size_t)bh * 64 * S_LEN;
  f32x4 acc[2][2] = {};

  for (int k0 = k0base; k0 < k0base + S_LEN/KSPLIT; k0 += 64) {
    #pragma unroll
    for (int j = 0; j < 4; ++j) {
      int cchunk = wid*4 + j;
      int r = (cchunk & 7) * 8 + (lane >> 3);
      int colb = (lane & 7) * 16;
      int scol = colb ^ ((r & 7) << 4);
      const bf16* src = (cchunk < 8) ? Kh : Vh;
      bf16* dst = ((cchunk < 8) ? Ks : Vs) + (size_t)(cchunk & 7) * 8 * 64;
      gll16(src + (size_t)r * S_LEN + k0 + (scol >> 1), dst);
    }
    __syncthreads();
    #pragma unroll
    for (int ksb = 0; ksb < 2; ++ksb) {
      bf16x8 af[2], bv[2];
      #pragma unroll
      for (int m = 0; m < 2; ++m) {
        int R = wm*32 + m*16 + (lane & 15);
        int cb = (ksb*64 + ((lane >> 4) << 4)) ^ ((R & 7) << 4);
        af[m] = *(const bf16x8*)((const char*)Ks + R*128 + cb);
      }
      #pragma unroll
      for (int n = 0; n < 2; ++n) {
        int R = wn*32 + n*16 + (lane & 15);
        int cb = (ksb*64 + ((lane >> 4) << 4)) ^ ((R & 7) << 4);
        bv[n] = *(const bf16x8*)((const char*)Vs + R*128 + cb);
      }
      #pragma unroll
      for (int m = 0; m < 2; ++m)
        #pragma unroll
        for (int n = 0; n < 2; ++n)
          acc[m][n] = MFMA_BF16(af[m], bv[n], acc[m][n]);
    }
    __syncthreads();
  }

  #pragma unroll
  for (int m = 0; m < 2; ++m)
    #pragma unroll
    for (int n = 0; n < 2; ++n)
      #pragma unroll
      for (int i = 0; i < 4; ++i) {
        int dd = wm*32 + m*16 + ((lane >> 4) << 2) + i;
        int vv = wn*32 + n*16 + (lane & 15);
        atomicAdd(&KVg[(size_t)bh*4096 + dd*64 + vv], acc[m][n][i]);
      }
}

// ---------------- out_pre = (Qp @ KV) / Z ----------------
__global__ __launch_bounds__(256) void attn_out(const bf16* __restrict__ QKV,
                                                const float* __restrict__ KVg,
                                                const float* __restrict__ Ksumg,
                                                bf16* __restrict__ OP) {
  const int head = blockIdx.x, stile = blockIdx.y;
  const int b = head >> 4, hh = head & 15;
  const int tid = threadIdx.x;
  const int wid = tid >> 6, lane = tid & 63;
  const int s0 = stile * 128;
  __shared__ __align__(16) bf16 Qs[128*64];
  __shared__ __align__(16) bf16 KVt[64*64];
  __shared__ float ksum_s[64];
  __shared__ float rZ[128];

  const float* KVh = KVg + (size_t)head*4096;
  #pragma unroll
  for (int i = 0; i < 16; ++i) {
    int idx = i*256 + tid;
    int dd = idx >> 6, vv = idx & 63;
    KVt[vv*64 + dd] = (bf16)KVh[idx];
  }
  if (tid < 64) ksum_s[tid] = Ksumg[head*64 + tid];
  #pragma unroll
  for (int p = 0; p < 4; ++p) {
    int row = p*32 + wid*8 + (lane >> 3);
    gll16(QKV + ((size_t)(s0+row)*BATCHN + b)*NQKV + hh*64 + ((lane&7)<<3),
          Qs + (p*32 + wid*8)*64);
  }
  __syncthreads();

  if (tid < 128) {
    float z = 0.f;
    #pragma unroll
    for (int dd = 0; dd < 64; ++dd) z += (float)Qs[tid*64 + dd] * ksum_s[dd];
    rZ[tid] = 1.f / (z + 1e-6f);
  }
  __syncthreads();

  f32x4 acc[2][4] = {};
  #pragma unroll
  for (int ksb = 0; ksb < 2; ++ksb) {
    bf16x8 af[2], bv[4];
    #pragma unroll
    for (int m = 0; m < 2; ++m)
      af[m] = *(const bf16x8*)(Qs + (wid*32 + m*16 + (lane & 15))*64 + ksb*32 + ((lane>>4)<<3));
    #pragma unroll
    for (int n = 0; n < 4; ++n)
      bv[n] = *(const bf16x8*)(KVt + (n*16 + (lane & 15))*64 + ksb*32 + ((lane>>4)<<3));
    #pragma unroll
    for (int m = 0; m < 2; ++m)
      #pragma unroll
      for (int n = 0; n < 4; ++n)
        acc[m][n] = MFMA_BF16(af[m], bv[n], acc[m][n]);
  }

  #pragma unroll
  for (int m = 0; m < 2; ++m)
    #pragma unroll
    for (int n = 0; n < 4; ++n)
      #pragma unroll
      for (int i = 0; i < 4; ++i) {
        int row = wid*32 + m*16 + ((lane >> 4) << 2) + i;
        int vv  = n*16 + (lane & 15);
        float val = acc[m][n][i] * rZ[row];
        OP[((size_t)(s0+row)*BATCHN + b)*DMODEL + hh*64 + vv] = (bf16)val;
      }
}

// ---------------- launch ----------------
extern "C" void kernel_launch(void* const* d_in, const int* in_sizes, int n_in,
                              void* d_out, int out_size, void* d_ws, size_t ws_size,
                              hipStream_t stream) {
  const float* h  = (const float*)d_in[0];
  const float* x  = (const float*)d_in[1];
  const float* Wq = (const float*)d_in[2];
  const float* bq = (const float*)d_in[3];
  const float* Wk = (const float*)d_in[4];
  const float* bk = (const float*)d_in[5];
  const float* Wv = (const float*)d_in[6];
  const float* bv = (const float*)d_in[7];
  const float* Wo = (const float*)d_in[8];
  const float* bo = (const float*)d_in[9];

  char* ws = (char*)d_ws;
  bf16*  hbf  = (bf16*)(ws);                    // 33,554,432 B  (reused as Kt)
  bf16*  xbf  = (bf16*)(ws + 33554432);         // 33,554,432 B  (reused as Vt)
  bf16*  wcat = (bf16*)(ws + 67108864);         //  6,291,456 B  [3072][1024]
  bf16*  wob  = (bf16*)(ws + 73400320);         //  2,097,152 B  [1024][1024]
  bf16*  qkv  = (bf16*)(ws + 75497472);         // 100,663,296 B [16384][3072]
  float* kvb  = (float*)(ws + 176160768);       //  1,048,576 B  [64][64][64]
  float* ksb  = (float*)(ws + 177209344);       //     16,384 B  [64][64]
  bf16*  op   = (bf16*)(ws + 177225728);        // 33,554,432 B  [16384][1024]

  bf16* Kt = hbf;
  bf16* Vt = xbf;

  cast_bf16<<<dim3(2048), 256, 0, stream>>>(h, hbf, MROWS*KDIM);
  cast_bf16<<<dim3(2048), 256, 0, stream>>>(x, xbf, MROWS*KDIM);
  cast_bf16<<<dim3(512),  256, 0, stream>>>(Wq, wcat,           1048576);
  cast_bf16<<<dim3(512),  256, 0, stream>>>(Wk, wcat + 1048576, 1048576);
  cast_bf16<<<dim3(512),  256, 0, stream>>>(Wv, wcat + 2097152, 1048576);
  cast_bf16<<<dim3(512),  256, 0, stream>>>(Wo, wob,            1048576);

  hipMemsetAsync(kvb, 0, 1048576 + 16384, stream);

  gemm256<0><<<dim3(768), 512, 0, stream>>>(hbf, xbf, wcat, bq, bk, bv, qkv);
  transpose_kv<<<dim3(64, 32), 256, 0, stream>>>(qkv, Kt, Vt, ksb);
  kv_gemm<<<dim3(64, KSPLIT), 256, 0, stream>>>(Kt, Vt, kvb);
  attn_out<<<dim3(64, 32), 256, 0, stream>>>(qkv, kvb, ksb, op);
  gemm256<1><<<dim3(256), 512, 0, stream>>>(op, nullptr, wob, bo, nullptr, nullptr, d_out);
}